// Round 1
// baseline (172.585 us; speedup 1.0000x reference)
//
#include <hip/hip_runtime.h>
#include <math.h>

#define EMBED 512
#define NQ 8
#define SEQ 2048
#define NB 8
#define LOG2E 1.4426950408889634f

typedef float vfloat4 __attribute__((ext_vector_type(4)));

// ---------------------------------------------------------------------------
// k1: rotT[b][q][i] = sum_e x[b][i][e] * R[e][q]   (unchanged — at its 32 MiB
// read roofline, ~6 µs). R transposed through LDS (stride 516, conflict-free
// b128); thread (q = tid&7, rslot = tid>>3) does one K=512 dot with vfloat4.
// ---------------------------------------------------------------------------
#define RPAD 516

__global__ __launch_bounds__(256) void qa_rot(
    const float* __restrict__ x, const float* __restrict__ R,
    float* __restrict__ rotT) {
    __shared__ float rt[NQ * RPAD];
#pragma unroll
    for (int m = 0; m < (EMBED * NQ) / 256; ++m) {
        int f = threadIdx.x + m * 256;
        rt[(f & 7) * RPAD + (f >> 3)] = R[f];
    }
    __syncthreads();

    const int q = threadIdx.x & 7;
    const int rslot = threadIdx.x >> 3;           // 0..31
    const int b = blockIdx.x >> 6;                // 64 blocks per batch
    const int i = ((blockIdx.x & 63) << 5) + rslot;

    const vfloat4* __restrict__ xr =
        (const vfloat4*)(x + ((size_t)b * SEQ + i) * EMBED);
    const vfloat4* __restrict__ rr = (const vfloat4*)(rt + q * RPAD);

    vfloat4 acc = {0.f, 0.f, 0.f, 0.f};           // 4 independent chains
#pragma unroll 8
    for (int m = 0; m < EMBED / 4; ++m) {
        acc += xr[m] * rr[m];                     // packed fma
    }
    rotT[(size_t)b * (NQ * SEQ) + (size_t)q * SEQ + i] =
        (acc.x + acc.y) + (acc.z + acc.w);
}

// ---------------------------------------------------------------------------
// k2 (restructured): scores[b][i][j] = sigmoid(rot_i . rot_j) / rowsum.
//
// Two-pass recompute, TI=4: pass A computes the rowsums only (no prob
// retention -> no pv[8][TI] register hoard), pass B recomputes dot+sigmoid
// (bit-identical ops) and stores each 256-j tile immediately, so stores
// interleave with VALU/trans work instead of bursting at the end.
//
// TI=4 -> 32 rows/block -> grid = 8*64 = 512 = exactly 2 blocks/CU on 256
// CUs: ONE residency round (previous version: grid 1024 = two lockstep
// rounds of stage->compute->store-burst). LDS panel reads per output row
// are halved vs TI=2. ~80 VGPRs live (ri[4][8]=32 + s[4]=16 + misc), well
// under the (512,4) 128-reg cap — no spill.
// ---------------------------------------------------------------------------
#define K2_THREADS 512
#define TI 4
#define ROWS_PER_BLOCK 32   // 8 waves * TI

__device__ __forceinline__ vfloat4 sigmoid4(vfloat4 s) {
    vfloat4 p;
    p.x = __builtin_amdgcn_rcpf(1.f + __builtin_amdgcn_exp2f(-s.x * LOG2E));
    p.y = __builtin_amdgcn_rcpf(1.f + __builtin_amdgcn_exp2f(-s.y * LOG2E));
    p.z = __builtin_amdgcn_rcpf(1.f + __builtin_amdgcn_exp2f(-s.z * LOG2E));
    p.w = __builtin_amdgcn_rcpf(1.f + __builtin_amdgcn_exp2f(-s.w * LOG2E));
    return p;
}

__global__ __launch_bounds__(K2_THREADS, 4) void qa_scores(
    const float* __restrict__ rotT, float* __restrict__ out) {
    __shared__ float lds[NQ * SEQ];               // 64 KiB, [q][j]
    const int b = blockIdx.x >> 6;                // 64 blocks per batch
    const int i0blk = (blockIdx.x & 63) * ROWS_PER_BLOCK;
    const float* __restrict__ rt = rotT + (size_t)b * (NQ * SEQ);

    // Stage rotT[b] (16384 floats) cooperatively, coalesced 16B.
    {
        const vfloat4* __restrict__ src = (const vfloat4*)rt;
        vfloat4* dst = (vfloat4*)lds;
#pragma unroll
        for (int m = 0; m < (NQ * SEQ / 4) / K2_THREADS; ++m)
            dst[threadIdx.x + m * K2_THREADS] = src[threadIdx.x + m * K2_THREADS];
    }
    __syncthreads();

    const int wave = threadIdx.x >> 6;            // 0..7
    const int lane = threadIdx.x & 63;
    const int i0 = i0blk + wave * TI;

    // rot_i for this wave's 4 rows (broadcast LDS reads).
    float ri[TI][NQ];
#pragma unroll
    for (int r = 0; r < TI; ++r)
#pragma unroll
        for (int q = 0; q < NQ; ++q)
            ri[r][q] = lds[q * SEQ + i0 + r];

    // ---- Pass A: rowsums only. Lane owns j = t*256 + 4*lane .. +3. ----
    float rsum[TI] = {0.f, 0.f, 0.f, 0.f};
#pragma unroll
    for (int t = 0; t < 8; ++t) {
        vfloat4 s[TI];
#pragma unroll
        for (int r = 0; r < TI; ++r) s[r] = (vfloat4){0.f, 0.f, 0.f, 0.f};
#pragma unroll
        for (int q = 0; q < NQ; ++q) {            // q-outer: one rj live
            vfloat4 rj = *((const vfloat4*)(lds + q * SEQ + t * 256) + lane);
#pragma unroll
            for (int r = 0; r < TI; ++r)
                s[r] += rj * ri[r][q];            // packed fma
        }
#pragma unroll
        for (int r = 0; r < TI; ++r) {
            vfloat4 p = sigmoid4(s[r]);
            rsum[r] += (p.x + p.y) + (p.z + p.w);
        }
    }

    // Butterfly reduce rowsums over 64 lanes; keep inverse.
    float rinv[TI];
#pragma unroll
    for (int r = 0; r < TI; ++r) {
#pragma unroll
        for (int off = 32; off > 0; off >>= 1)
            rsum[r] += __shfl_xor(rsum[r], off);
        rinv[r] = __builtin_amdgcn_rcpf(rsum[r]);
    }

    // ---- Pass B: recompute (bit-identical), normalize, store per tile. ----
    float* __restrict__ orow0 = out + ((size_t)b * SEQ + i0) * SEQ;
#pragma unroll
    for (int t = 0; t < 8; ++t) {
        vfloat4 s[TI];
#pragma unroll
        for (int r = 0; r < TI; ++r) s[r] = (vfloat4){0.f, 0.f, 0.f, 0.f};
#pragma unroll
        for (int q = 0; q < NQ; ++q) {
            vfloat4 rj = *((const vfloat4*)(lds + q * SEQ + t * 256) + lane);
#pragma unroll
            for (int r = 0; r < TI; ++r)
                s[r] += rj * ri[r][q];
        }
#pragma unroll
        for (int r = 0; r < TI; ++r) {
            vfloat4 v = sigmoid4(s[r]) * rinv[r];
            __builtin_nontemporal_store(
                v, (vfloat4*)(orow0 + (size_t)r * SEQ + t * 256) + lane);
        }
    }
}

// ---------------------------------------------------------------------------
extern "C" void kernel_launch(void* const* d_in, const int* in_sizes, int n_in,
                              void* d_out, int out_size, void* d_ws, size_t ws_size,
                              hipStream_t stream) {
    const float* x        = (const float*)d_in[0];  // (8, 2048, 512) fp32
    const float* rotation = (const float*)d_in[1];  // (512, 8) fp32
    float* out = (float*)d_out;                     // (8, 2048, 2048) fp32

    float* rotT = (float*)d_ws;                     // 8 x 8 x 2048 = 512 KiB

    qa_rot<<<NB * 64, 256, 0, stream>>>(x, rotation, rotT);
    qa_scores<<<NB * 64, K2_THREADS, 0, stream>>>(rotT, out);
}